// Round 8
// baseline (270.389 us; speedup 1.0000x reference)
//
#include <hip/hip_runtime.h>

#define B_   64
#define P_   12273
#define J_   80
#define MOT_ 94
#define K_   64
#define H_   128
#define Q_   340      // NB*WN
#define NE_  36819    // P*3
#define MK_  6016     // MOT*K
#define PW_  12288    // padded P for w_t rows
#define QH_  170      // Q/2 per k_detail half

typedef float v4f  __attribute__((ext_vector_type(4)));
typedef float v8f  __attribute__((ext_vector_type(8)));
typedef float v16f __attribute__((ext_vector_type(16)));
#define AS4 __attribute__((address_space(4)))

__device__ __forceinline__ const AS4 float* unif(const float* p){
  return (const AS4 float*)(unsigned long long)p;
}
__device__ __forceinline__ const AS4 v4f* univ4(const float* p){
  return (const AS4 v4f*)(unsigned long long)p;
}
__device__ __forceinline__ const AS4 v16f* univ16(const float* p){
  return (const AS4 v16f*)(unsigned long long)p;
}

// ---- K1 "prep": fused fieldnet + tm transpose + skin transpose + lacc init
__global__ __launch_bounds__(256) void k_prep(
    const float* __restrict__ query, const float* __restrict__ mwl,
    const float* __restrict__ tm,    const float* __restrict__ W1,
    const float* __restrict__ b1,    const float* __restrict__ W2,
    const float* __restrict__ b2,    const float* __restrict__ cps,
    const float* __restrict__ cpm,   const float* __restrict__ cts,
    const float* __restrict__ ctm,   const float* __restrict__ skin,
    float* __restrict__ G,           float* __restrict__ tm_t,
    float* __restrict__ w_t,         float* __restrict__ lacc)
{
  __shared__ float smem[80 * 65];
  int blk = blockIdx.x;
  int t = threadIdx.x;
  if (blk < 1280){
    int lane = t & 63;
    int wid = __builtin_amdgcn_readfirstlane(t >> 6);
    int bj = blk * 4 + wid;
    int b = bj / J_, l = bj - b * J_;
    float* hs = smem + wid * 80;
    float acc = 0.f;
    const AS4 float* mp = unif(mwl + l * MOT_);
    const float* tp = tm + (size_t)b * MK_ + lane;
    #pragma unroll 2
    for (int j = 0; j < MOT_; j++){
      float w = mp[j]; w = w > 0.f ? w : 0.f;
      acc = fmaf(w, tp[j * K_], acc);
    }
    hs[3 + lane] = acc;
    if (lane < 3) hs[lane] = query[(size_t)bj * 3 + lane];
    __syncthreads();
    float a1 = b1[lane], a2 = b1[lane + 64];
    for (int i = 0; i < 3 + K_; i++){
      float hv = hs[i];
      a1 = fmaf(hv, W1[i * H_ + lane], a1);
      a2 = fmaf(hv, W1[i * H_ + 64 + lane], a2);
    }
    a1 = a1 > 0.f ? a1 : 0.f;
    a2 = a2 > 0.f ? a2 : 0.f;
    const AS4 float* b2c = unif(b2);
    float rt[6];
    #pragma unroll
    for (int o = 0; o < 6; o++){
      float po = fmaf(a1, W2[lane * 6 + o], a2 * W2[(lane + 64) * 6 + o]);
      #pragma unroll
      for (int off = 32; off; off >>= 1) po += __shfl_xor(po, off);
      rt[o] = po + b2c[o];
    }
    const float D2R = 0.017453292519943295f;
    float ax = fmaf(rt[0], cps[0], cpm[0]) * D2R;
    float ay = fmaf(rt[1], cps[1], cpm[1]) * D2R;
    float az = fmaf(rt[2], cps[2], cpm[2]) * D2R;
    float tx = fmaf(hs[0] + rt[3], cts[0], ctm[0]);
    float ty = fmaf(hs[1] + rt[4], cts[1], ctm[1]);
    float tz = fmaf(hs[2] + rt[5], cts[2], ctm[2]);
    float sx, cx, sy, cy, sz, cz;
    sincosf(ax, &sx, &cx); sincosf(ay, &sy, &cy); sincosf(az, &sz, &cz);
    if (lane == 0){
      float4 r0 = make_float4(cz*cy, cz*sy*sx - sz*cx, cz*sy*cx + sz*sx, tx);
      float4 r1 = make_float4(sz*cy, sz*sy*sx + cz*cx, sz*sy*cx - cz*sx, ty);
      float4 r2 = make_float4(-sy,   cy*sx,            cy*cx,            tz);
      float4* g = (float4*)(G + (size_t)bj * 12);
      g[0] = r0; g[1] = r1; g[2] = r2;
    }
  } else if (blk < 1374){
    int m0 = (blk - 1280) * 64;
    int ml = t & 63, g = t >> 6;
    #pragma unroll
    for (int r = 0; r < 16; r++){
      int b = g * 16 + r;
      smem[ml * 65 + b] = tm[(size_t)b * MK_ + m0 + ml];
    }
    __syncthreads();
    int bl = t & 63;
    #pragma unroll
    for (int r = 0; r < 16; r++){
      int m = g * 16 + r;
      tm_t[(size_t)(m0 + m) * 64 + bl] = smem[m * 65 + bl];
    }
  } else if (blk < 1566){
    int p0 = (blk - 1374) * 64;
    #pragma unroll
    for (int k = 0; k < 20; k++){
      int idx = k * 256 + t;
      int pl = idx / 80, j = idx - pl * 80;
      int p = p0 + pl;
      smem[j * 65 + pl] = (p < P_) ? skin[(size_t)p * J_ + j] : 0.f;
    }
    __syncthreads();
    #pragma unroll
    for (int k = 0; k < 20; k++){
      int idx = k * 256 + t;
      int j = idx >> 6, pl = idx & 63;
      w_t[(size_t)j * PW_ + p0 + pl] = smem[j * 65 + pl];
    }
  } else {
    if (t < 2) lacc[t] = 0.f;
  }
}

// ---- K2: detailkey partial GEMM (unchanged from round 7)
__global__ __launch_bounds__(256) void k_dkey(
    const float* __restrict__ tm_t, const float* __restrict__ Wd,
    float* __restrict__ part)
{
  int t = threadIdx.x;
  int lane = t & 63;
  int wid = __builtin_amdgcn_readfirstlane(t >> 6);
  int qt = blockIdx.x;
  int q = qt * 64 + lane;
  bool vq = q < Q_;
  int m0 = blockIdx.y * 64;
  const AS4 v16f* tr = univ16(tm_t);
  float acc[16];
  #pragma unroll
  for (int i = 0; i < 16; i++) acc[i] = 0.f;
  float wbuf[4];
  #pragma unroll
  for (int i = 0; i < 4; i++)
    wbuf[i] = vq ? Wd[(size_t)(m0 + i) * Q_ + q] : 0.f;
  v16f tb0 = tr[(size_t)(m0 + 0) * 4 + wid];
  v16f tb1 = tr[(size_t)(m0 + 1) * 4 + wid];
  #pragma unroll 4
  for (int mm = 0; mm < 60; mm++){
    float wd = wbuf[mm & 3];
    wbuf[mm & 3] = vq ? Wd[(size_t)(m0 + mm + 4) * Q_ + q] : 0.f;
    v16f tv = tb0; tb0 = tb1;
    tb1 = tr[(size_t)(m0 + mm + 2) * 4 + wid];
    #pragma unroll
    for (int i = 0; i < 16; i++) acc[i] = fmaf(tv[i], wd, acc[i]);
  }
  #pragma unroll
  for (int mm = 60; mm < 64; mm++){
    float wd = wbuf[mm & 3];
    v16f tv = tb0; tb0 = tb1;
    if (mm < 62) tb1 = tr[(size_t)(m0 + mm + 2) * 4 + wid];
    #pragma unroll
    for (int i = 0; i < 16; i++) acc[i] = fmaf(tv[i], wd, acc[i]);
  }
  float* pb = part + ((size_t)blockIdx.y * 6 + qt) * 4096 + (size_t)(wid * 16) * 64;
  #pragma unroll
  for (int i = 0; i < 16; i++) pb[i * 64 + lane] = acc[i];
}

// ---- K3: reduce partials + bd -> dk_t[q*64+b] (unchanged)
__global__ __launch_bounds__(256) void k_dkred(
    const float* __restrict__ part, const float* __restrict__ bd,
    float* __restrict__ dk_t, int S)
{
  int t = threadIdx.x;
  int jj = blockIdx.x * 32 + (t >> 3);
  int dl = t & 7;
  int b = jj / Q_, q = jj - b * Q_;
  int qt = q >> 6, ql = q & 63;
  const float* pp = part + (size_t)qt * 4096 + b * 64 + ql;
  float s = 0.f;
  for (int d = dl; d < S; d += 8) s += pp[(size_t)d * 6 * 4096];
  s += __shfl_xor(s, 1); s += __shfl_xor(s, 2); s += __shfl_xor(s, 4);
  if (dl == 0) dk_t[q * 64 + b] = bd[q] + s;
}

// ---- K4: detail einsum v3. dk rows staged in LDS (43.5 KB), 2 e-cols/thread.
//      grid (288, 2): y = q-half. y==1 -> out[1..], y==0 -> stg0 (raw accum,
//      scale applied in k_skin).
__global__ __launch_bounds__(512) void k_detail(
    const float* __restrict__ DPSD, const float* __restrict__ dk_t,
    float* __restrict__ stg0, float* __restrict__ out,
    float* __restrict__ lacc)
{
  __shared__ float lds[QH_ * 64];                    // 43520 B
  int t = threadIdx.x;
  int lane = t & 63;
  int wid = __builtin_amdgcn_readfirstlane(t >> 6);  // 0..7
  int b0 = wid * 8;
  int e  = blockIdx.x * 128 + lane;                  // max 36799 < NE_
  int e2 = e + 64;
  bool v2 = e2 < NE_;
  int q0 = blockIdx.y * QH_;
  // stage dk_t[q0..q0+170)[0..64) -> LDS (linear, coalesced)
  {
    const float4* src = (const float4*)(dk_t + (size_t)q0 * 64);
    float4* dst = (float4*)lds;
    for (int i = t; i < QH_ * 16; i += 512) dst[i] = src[i];
  }
  __syncthreads();
  const float* Dp = DPSD + e;
  float acc[8][2];
  #pragma unroll
  for (int i = 0; i < 8; i++){ acc[i][0] = 0.f; acc[i][1] = 0.f; }
  float sq = 0.f;
  float dcA[5], dcB[5], dnA[5], dnB[5];
  #pragma unroll
  for (int i = 0; i < 5; i++){
    size_t ro = (size_t)(q0 + i) * NE_;
    dcA[i] = Dp[ro];
    dcB[i] = v2 ? Dp[ro + 64] : 0.f;
  }
  const int NG = QH_ / 5;                            // 34
  for (int g = 0; g < NG; g++){
    int qq = g * 5;
    if (g + 1 < NG){
      #pragma unroll
      for (int i = 0; i < 5; i++){
        size_t ro = (size_t)(q0 + qq + 5 + i) * NE_;
        dnA[i] = Dp[ro];
        dnB[i] = v2 ? Dp[ro + 64] : 0.f;
      }
    }
    if (wid == 0){
      #pragma unroll
      for (int i = 0; i < 5; i++){
        sq = fmaf(dcA[i], dcA[i], sq);
        sq = fmaf(dcB[i], dcB[i], sq);
      }
    }
    #pragma unroll
    for (int i = 0; i < 5; i++){
      const float4* lp = (const float4*)(lds + (qq + i) * 64 + b0);
      float4 r0 = lp[0];                             // ds_read_b128 broadcast
      float4 r1 = lp[1];
      float dA = dcA[i], dB = dcB[i];
      acc[0][0] = fmaf(r0.x, dA, acc[0][0]); acc[0][1] = fmaf(r0.x, dB, acc[0][1]);
      acc[1][0] = fmaf(r0.y, dA, acc[1][0]); acc[1][1] = fmaf(r0.y, dB, acc[1][1]);
      acc[2][0] = fmaf(r0.z, dA, acc[2][0]); acc[2][1] = fmaf(r0.z, dB, acc[2][1]);
      acc[3][0] = fmaf(r0.w, dA, acc[3][0]); acc[3][1] = fmaf(r0.w, dB, acc[3][1]);
      acc[4][0] = fmaf(r1.x, dA, acc[4][0]); acc[4][1] = fmaf(r1.x, dB, acc[4][1]);
      acc[5][0] = fmaf(r1.y, dA, acc[5][0]); acc[5][1] = fmaf(r1.y, dB, acc[5][1]);
      acc[6][0] = fmaf(r1.z, dA, acc[6][0]); acc[6][1] = fmaf(r1.z, dB, acc[6][1]);
      acc[7][0] = fmaf(r1.w, dA, acc[7][0]); acc[7][1] = fmaf(r1.w, dB, acc[7][1]);
    }
    #pragma unroll
    for (int i = 0; i < 5; i++){ dcA[i] = dnA[i]; dcB[i] = dnB[i]; }
  }
  {
    bool toOut = (blockIdx.y == 1);
    float* dst = toOut ? (out + 1) : stg0;
    #pragma unroll
    for (int i = 0; i < 8; i++){
      size_t rb = (size_t)(b0 + i) * NE_;
      dst[rb + e] = acc[i][0];
      if (v2) dst[rb + e2] = acc[i][1];
    }
  }
  if (wid == 0){
    #pragma unroll
    for (int off = 32; off; off >>= 1) sq += __shfl_xor(sq, off);
    if (lane == 0) atomicAdd(&lacc[1], sq);
  }
}

// ---- K5: LBS skinning (unchanged from round 7; always combines both halves)
__global__ __launch_bounds__(256) void k_skin(
    const float* __restrict__ G, const float* __restrict__ w_t,
    const float* __restrict__ rest, const float* __restrict__ in_pc,
    const float* __restrict__ stg0, const float* __restrict__ rstd,
    const float* __restrict__ rmean,
    float* __restrict__ out, float* __restrict__ lacc)
{
  int t = threadIdx.x;
  int lane = t & 63;
  int wid = __builtin_amdgcn_readfirstlane(t >> 6);
  int p  = blockIdx.x * 64 + lane;
  int bA = blockIdx.y * 8 + wid * 2;
  const AS4 v4f* gA = univ4(G + (size_t)bA * J_ * 12);
  const AS4 v4f* gB = univ4(G + ((size_t)bA + 1) * J_ * 12);
  float accA[12], accB[12];
  #pragma unroll
  for (int c = 0; c < 12; c++){ accA[c] = 0.f; accB[c] = 0.f; }
  const float* wp = w_t + p;
  #pragma unroll 4
  for (int j = 0; j < J_; j++){
    float w = wp[(size_t)j * PW_];
    v4f a0 = gA[j * 3 + 0], a1 = gA[j * 3 + 1], a2 = gA[j * 3 + 2];
    v4f c0 = gB[j * 3 + 0], c1 = gB[j * 3 + 1], c2 = gB[j * 3 + 2];
    #pragma unroll
    for (int c = 0; c < 4; c++){
      accA[c]     = fmaf(w, a0[c], accA[c]);
      accA[4 + c] = fmaf(w, a1[c], accA[4 + c]);
      accA[8 + c] = fmaf(w, a2[c], accA[8 + c]);
      accB[c]     = fmaf(w, c0[c], accB[c]);
      accB[4 + c] = fmaf(w, c1[c], accB[4 + c]);
      accB[8 + c] = fmaf(w, c2[c], accB[8 + c]);
    }
  }
  bool vp = p < P_;
  float vx = 0.f, vy = 0.f, vz = 0.f;
  if (vp){ vx = rest[p * 3]; vy = rest[p * 3 + 1]; vz = rest[p * 3 + 2]; }
  float srs[3], srm[3];
  #pragma unroll
  for (int x = 0; x < 3; x++){ srs[x] = rstd[x]; srm[x] = rmean[x]; }
  float lsum = 0.f;
  if (vp){
    size_t baseA = ((size_t)bA * P_ + p) * 3;
    size_t baseB = baseA + (size_t)P_ * 3;
    #pragma unroll
    for (int x = 0; x < 3; x++){
      float det = out[1 + baseA + x] + stg0[baseA + x];
      float v = fmaf(accA[x*4+0], vx, fmaf(accA[x*4+1], vy, fmaf(accA[x*4+2], vz, accA[x*4+3])));
      v += fmaf(det, srs[x], srm[x]);
      lsum += fabsf(in_pc[baseA + x] - v);
      out[1 + baseA + x] = v;
    }
    #pragma unroll
    for (int x = 0; x < 3; x++){
      float det = out[1 + baseB + x] + stg0[baseB + x];
      float v = fmaf(accB[x*4+0], vx, fmaf(accB[x*4+1], vy, fmaf(accB[x*4+2], vz, accB[x*4+3])));
      v += fmaf(det, srs[x], srm[x]);
      lsum += fabsf(in_pc[baseB + x] - v);
      out[1 + baseB + x] = v;
    }
  }
  #pragma unroll
  for (int off = 32; off; off >>= 1) lsum += __shfl_xor(lsum, off);
  __shared__ float red[4];
  if (lane == 0) red[wid] = lsum;
  __syncthreads();
  if (t == 0) atomicAdd(&lacc[0], red[0] + red[1] + red[2] + red[3]);
}

// ---- K6: finalize scalar loss
__global__ void k_finalize(const float* __restrict__ lacc, float* __restrict__ out){
  if (threadIdx.x == 0 && blockIdx.x == 0){
    float loss = lacc[0] * (1.f / 2356416.f) + 1e-4f * (lacc[1] * (1.f / 12518460.f));
    out[0] = loss;
  }
}

extern "C" void kernel_launch(void* const* d_in, const int* in_sizes, int n_in,
                              void* d_out, int out_size, void* d_ws, size_t ws_size,
                              hipStream_t stream){
  const float* in_pc = (const float*)d_in[0];
  const float* rest  = (const float*)d_in[2];
  const float* skin  = (const float*)d_in[3];
  const float* mwl   = (const float*)d_in[4];
  const float* query = (const float*)d_in[5];
  const float* cps   = (const float*)d_in[6];
  const float* cpm   = (const float*)d_in[7];
  const float* cts   = (const float*)d_in[8];
  const float* ctm   = (const float*)d_in[9];
  const float* W1    = (const float*)d_in[10];
  const float* b1    = (const float*)d_in[11];
  const float* W2    = (const float*)d_in[12];
  const float* b2    = (const float*)d_in[13];
  const float* tm    = (const float*)d_in[14];
  const float* Wd    = (const float*)d_in[15];
  const float* bd    = (const float*)d_in[16];
  const float* DPSD  = (const float*)d_in[17];
  const float* rstd  = (const float*)d_in[18];
  const float* rmean = (const float*)d_in[19];
  float* out = (float*)d_out;

  float* ws   = (float*)d_ws;
  float* G    = ws;                 // 61440
  float* dk_t = G + 61440;          // 21760
  float* lacc = dk_t + 21760;       // 64 (pad)
  float* tm_t = lacc + 64;          // 385024
  float* w_t  = tm_t + 385024;      // 983040
  float* un   = w_t + 983040;       // union: part (94*24576) then stg0 (2356416)
  // (nqh=2 path proven in-budget on this harness in rounds 6-7)

  k_prep    <<<1567, 256, 0, stream>>>(query, mwl, tm, W1, b1, W2, b2,
                                       cps, cpm, cts, ctm, skin,
                                       G, tm_t, w_t, lacc);
  k_dkey    <<<dim3(6, 94), 256, 0, stream>>>(tm_t, Wd, un);
  k_dkred   <<<680, 256, 0, stream>>>(un, bd, dk_t, 94);
  k_detail  <<<dim3(288, 2), 512, 0, stream>>>(DPSD, dk_t, un, out, lacc);
  k_skin    <<<dim3(192, 8), 256, 0, stream>>>(G, w_t, rest, in_pc, un, rstd, rmean,
                                               out, lacc);
  k_finalize<<<1, 64, 0, stream>>>(lacc, out);
}